// Round 1
// baseline (677.373 us; speedup 1.0000x reference)
//
#include <hip/hip_runtime.h>

#define B_N 1024
#define X_N 1024
#define Y_N 16384
#define Z_N 1000

// output float offsets
#define OFF_ACT      0
#define OFF_MAXRESP  1
#define OFF_WX       1025
#define OFF_WZ       16778241
#define OFF_U        33162241
#define OFF_THR      49546241
#define OFF_AGE      49562625
#define OFF_ZAGE     49579009

// ws float offsets
#define WS_INV_X    0
#define WS_INV_WX   1024
#define WS_INV_WZ   17408
#define WS_INV_U    33792
#define WS_PMAX     34816   /* u64[1024] */
#define WS_PFB      36864   /* u64[1024] */
#define WS_FIDX     38912   /* int[1024] */
#define WS_CNT      39936   /* int[16384] */
#define WS_ZCNT     56320   /* int[1024] */
#define WS_SEGMIN   57344   /* uint[16384] */
#define WS_CTR      73728   /* int[8]: [0]=unact_cnt [1]=activated_cnt */

__device__ __forceinline__ unsigned enc_f(float f) {
    unsigned u = __float_as_uint(f);
    return (u & 0x80000000u) ? ~u : (u | 0x80000000u);
}
__device__ __forceinline__ float dec_f(unsigned e) {
    unsigned u = (e & 0x80000000u) ? (e ^ 0x80000000u) : ~e;
    return __uint_as_float(u);
}
__device__ __forceinline__ unsigned long long pack_vi(float v, int y) {
    return ((unsigned long long)enc_f(v) << 32) |
           (unsigned long long)(0xFFFFFFFFu - (unsigned)y);
}

__global__ void init_kernel(unsigned long long* pmax, unsigned long long* pfb,
                            int* cnt, unsigned* segmin, int* zcnt, int* ctr) {
    int i = blockIdx.x * 256 + threadIdx.x;
    if (i < B_N) { pmax[i] = 0ull; pfb[i] = 0ull; }
    if (i < Y_N) { cnt[i] = 0; segmin[i] = 0xFFFFFFFFu; }
    if (i < 1024) zcnt[i] = 0;
    if (i < 8) ctr[i] = 0;
}

__global__ void rownorm_kernel(const float* __restrict__ src, int rowlen,
                               float* __restrict__ inv_out) {
    int row = blockIdx.x;
    const float* p = src + (size_t)row * rowlen;
    float ss = 0.f;
    for (int e = threadIdx.x; e < rowlen; e += 256) { float v = p[e]; ss += v * v; }
    #pragma unroll
    for (int s = 32; s > 0; s >>= 1) ss += __shfl_xor(ss, s, 64);
    __shared__ float red[4];
    if ((threadIdx.x & 63) == 0) red[threadIdx.x >> 6] = ss;
    __syncthreads();
    if (threadIdx.x == 0) {
        float tot = red[0] + red[1] + red[2] + red[3];
        inv_out[row] = 1.0f / fmaxf(sqrtf(tot), 1e-12f);
    }
}

__global__ void unact_kernel(const float* __restrict__ y_age, int* ctr) {
    int i = blockIdx.x * 256 + threadIdx.x;
    int a = (y_age[i] < 1.0f) ? 1 : 0;
    unsigned long long m = __ballot(a);
    if ((threadIdx.x & 63) == 0) atomicAdd(ctr, (int)__popcll(m));
}

__global__ __launch_bounds__(256) void gemm_argmax_kernel(
    const float* __restrict__ x, const float* __restrict__ inv_x,
    const float* __restrict__ wxw, const float* __restrict__ inv_wx,
    const float* __restrict__ wzw, const float* __restrict__ inv_wz,
    const int* __restrict__ zlab, const float* __restrict__ y_age,
    unsigned long long* pmax, unsigned long long* pfb) {
    __shared__ float As[16][128];
    __shared__ float Bs[16][128];
    __shared__ int s_z[128];
    const int t = threadIdx.x;
    const int y0 = blockIdx.x * 128;
    const int b0 = blockIdx.y * 128;
    if (t < 128) s_z[t] = zlab[b0 + t];
    const int wrow = t >> 2;
    const int wk = (t & 3) << 2;
    const float* ap0 = x + (size_t)(b0 + wrow) * X_N + wk;
    const float* ap1 = ap0 + (size_t)64 * X_N;
    const float* bp0 = wxw + (size_t)(y0 + wrow) * X_N + wk;
    const float* bp1 = bp0 + (size_t)64 * X_N;
    const float ia0 = inv_x[b0 + wrow];
    const float ia1 = inv_x[b0 + 64 + wrow];
    const int ty = t >> 4, tx = t & 15;
    float acc[8][8];
    #pragma unroll
    for (int i = 0; i < 8; ++i)
        #pragma unroll
        for (int j = 0; j < 8; ++j) acc[i][j] = 0.f;

    for (int k0 = 0; k0 < X_N; k0 += 16) {
        float4 a0 = *reinterpret_cast<const float4*>(ap0 + k0);
        float4 a1 = *reinterpret_cast<const float4*>(ap1 + k0);
        float4 q0 = *reinterpret_cast<const float4*>(bp0 + k0);
        float4 q1 = *reinterpret_cast<const float4*>(bp1 + k0);
        __syncthreads();
        As[wk+0][wrow] = a0.x*ia0; As[wk+1][wrow] = a0.y*ia0;
        As[wk+2][wrow] = a0.z*ia0; As[wk+3][wrow] = a0.w*ia0;
        As[wk+0][64+wrow] = a1.x*ia1; As[wk+1][64+wrow] = a1.y*ia1;
        As[wk+2][64+wrow] = a1.z*ia1; As[wk+3][64+wrow] = a1.w*ia1;
        Bs[wk+0][wrow] = q0.x; Bs[wk+1][wrow] = q0.y;
        Bs[wk+2][wrow] = q0.z; Bs[wk+3][wrow] = q0.w;
        Bs[wk+0][64+wrow] = q1.x; Bs[wk+1][64+wrow] = q1.y;
        Bs[wk+2][64+wrow] = q1.z; Bs[wk+3][64+wrow] = q1.w;
        __syncthreads();
        #pragma unroll
        for (int k = 0; k < 16; ++k) {
            float4 alo = *reinterpret_cast<const float4*>(&As[k][ty*4]);
            float4 ahi = *reinterpret_cast<const float4*>(&As[k][64+ty*4]);
            float4 blo = *reinterpret_cast<const float4*>(&Bs[k][tx*4]);
            float4 bhi = *reinterpret_cast<const float4*>(&Bs[k][64+tx*4]);
            float av[8] = {alo.x,alo.y,alo.z,alo.w,ahi.x,ahi.y,ahi.z,ahi.w};
            float bv[8] = {blo.x,blo.y,blo.z,blo.w,bhi.x,bhi.y,bhi.z,bhi.w};
            #pragma unroll
            for (int i = 0; i < 8; ++i)
                #pragma unroll
                for (int j = 0; j < 8; ++j)
                    acc[i][j] = fmaf(av[i], bv[j], acc[i][j]);
        }
    }

    // epilogue: per-column scales hoisted
    float swx[8], swz[8], msk[8]; int ys[8];
    #pragma unroll
    for (int j = 0; j < 8; ++j) {
        int cloc = (j < 4) ? (tx*4 + j) : (64 + tx*4 + j - 4);
        int y = y0 + cloc;
        ys[j] = y;
        swx[j] = 0.5f * inv_wx[y];
        swz[j] = 0.5f * inv_wz[y];
        msk[j] = (y_age[y] < 1.0f) ? 1.0f : 0.0f;
    }
    #pragma unroll
    for (int i = 0; i < 8; ++i) {
        int rloc = (i < 4) ? (ty*4 + i) : (64 + ty*4 + i - 4);
        int b = b0 + rloc;
        int zb = s_z[rloc];
        unsigned long long bm = 0ull, bf = 0ull;
        #pragma unroll
        for (int j = 0; j < 8; ++j) {
            float val = acc[i][j]*swx[j] + swz[j]*wzw[(size_t)ys[j]*Z_N + zb];
            unsigned long long pm = pack_vi(val, ys[j]);
            unsigned long long pf = pack_vi(val*msk[j], ys[j]);
            bm = (pm > bm) ? pm : bm;
            bf = (pf > bf) ? pf : bf;
        }
        #pragma unroll
        for (int s = 1; s < 16; s <<= 1) {
            unsigned long long o = __shfl_xor(bm, s, 64);
            bm = (o > bm) ? o : bm;
            o = __shfl_xor(bf, s, 64);
            bf = (o > bf) ? o : bf;
        }
        if (tx == 0) {
            atomicMax(&pmax[b], bm);
            atomicMax(&pfb[b], bf);
        }
    }
}

__global__ void finalize_kernel(const unsigned long long* __restrict__ pmax,
                                const unsigned long long* __restrict__ pfb,
                                const float* __restrict__ y_thr,
                                const float* __restrict__ y_age,
                                const int* __restrict__ zlab,
                                const int* __restrict__ ctr,
                                int* final_idx, int* cnt, unsigned* segmin,
                                int* zcnt, float* __restrict__ out_maxresp) {
    int b = blockIdx.x * 256 + threadIdx.x;
    if (b >= B_N) return;
    unsigned long long pm = pmax[b];
    unsigned enc = (unsigned)(pm >> 32);
    int idx = (int)(0xFFFFFFFFu - (unsigned)(pm & 0xFFFFFFFFull));
    float mresp = dec_f(enc);
    out_maxresp[b] = mresp;
    bool judge = (mresp > y_thr[idx]) || (y_age[idx] < 1.0f);
    bool anyu = ctr[0] > 0;
    int fidx = (int)(0xFFFFFFFFu - (unsigned)(pfb[b] & 0xFFFFFFFFull));
    int fin = (judge || !anyu) ? idx : fidx;
    final_idx[b] = fin;
    atomicAdd(&cnt[fin], 1);
    atomicMin(&segmin[fin], enc);
    atomicAdd(&zcnt[zlab[b]], 1);
}

__global__ void wx_out_kernel(const float* __restrict__ wxw, const float* __restrict__ inv_wx,
                              const float* __restrict__ x, const float* __restrict__ inv_x,
                              const int* __restrict__ final_idx, const int* __restrict__ cnt,
                              const float* __restrict__ y_age, float* __restrict__ outw) {
    int j = blockIdx.x;
    int t = threadIdx.x;
    __shared__ int s_b[1024];
    __shared__ int s_n;
    if (t == 0) s_n = 0;
    __syncthreads();
    int c = cnt[j];
    if (c > 0) {
        for (int b = t; b < B_N; b += 256)
            if (final_idx[b] == j) { int p = atomicAdd(&s_n, 1); s_b[p] = b; }
    }
    __syncthreads();
    float inv = inv_wx[j];
    float lr = 1.0f / (y_age[j] + 1.0f);
    float fc = (float)c;
    float dv = (c > 0) ? fc : 1.0f;
    int n = s_n;
    float4 w = *reinterpret_cast<const float4*>(wxw + (size_t)j * X_N + t * 4);
    float4 wn = make_float4(w.x*inv, w.y*inv, w.z*inv, w.w*inv);
    if (c > 0) {
        float4 s = make_float4(0.f, 0.f, 0.f, 0.f);
        for (int m = 0; m < n; ++m) {
            int b = s_b[m];
            float ix = inv_x[b];
            float4 xv = *reinterpret_cast<const float4*>(x + (size_t)b * X_N + t * 4);
            s.x += xv.x * ix; s.y += xv.y * ix; s.z += xv.z * ix; s.w += xv.w * ix;
        }
        float f = lr / dv;
        wn.x += f * (s.x - fc * wn.x);
        wn.y += f * (s.y - fc * wn.y);
        wn.z += f * (s.z - fc * wn.z);
        wn.w += f * (s.w - fc * wn.w);
    }
    *reinterpret_cast<float4*>(outw + (size_t)j * X_N + t * 4) = wn;
}

__global__ void wz_out_kernel(const float* __restrict__ wzw, const float* __restrict__ inv_wz,
                              const int* __restrict__ zlab, const int* __restrict__ final_idx,
                              const int* __restrict__ cnt, const float* __restrict__ y_age,
                              float* __restrict__ outw) {
    int j = blockIdx.x;
    int t = threadIdx.x;
    __shared__ int s_c[1024];
    __shared__ int s_n;
    if (t == 0) s_n = 0;
    __syncthreads();
    int c = cnt[j];
    if (c > 0) {
        for (int b = t; b < B_N; b += 256)
            if (final_idx[b] == j) { int p = atomicAdd(&s_n, 1); s_c[p] = zlab[b]; }
    }
    __syncthreads();
    if (t >= 250) return;
    float inv = inv_wz[j];
    float lr = 1.0f / (y_age[j] + 1.0f);
    float fc = (float)c;
    float dv = (c > 0) ? fc : 1.0f;
    int n = s_n;
    float4 w = *reinterpret_cast<const float4*>(wzw + (size_t)j * Z_N + t * 4);
    float4 wn = make_float4(w.x*inv, w.y*inv, w.z*inv, w.w*inv);
    if (c > 0) {
        float4 s = make_float4(0.f, 0.f, 0.f, 0.f);
        for (int m = 0; m < n; ++m) {
            int d = s_c[m] - t * 4;
            if (d == 0) s.x += 1.f;
            else if (d == 1) s.y += 1.f;
            else if (d == 2) s.z += 1.f;
            else if (d == 3) s.w += 1.f;
        }
        float f = lr / dv;
        wn.x += f * (s.x - fc * wn.x);
        wn.y += f * (s.y - fc * wn.y);
        wn.z += f * (s.z - fc * wn.z);
        wn.w += f * (s.w - fc * wn.w);
    }
    *reinterpret_cast<float4*>(outw + (size_t)j * Z_N + t * 4) = wn;
}

__global__ void u_out_kernel(const float* __restrict__ uw, const float* __restrict__ inv_u,
                             const int* __restrict__ zlab, const int* __restrict__ final_idx,
                             const int* __restrict__ zcnt, const float* __restrict__ z_age,
                             float* __restrict__ outw) {
    int cz = blockIdx.x;
    int t = threadIdx.x;
    __shared__ int s_w[1024];
    __shared__ int s_n;
    if (t == 0) s_n = 0;
    __syncthreads();
    int c = zcnt[cz];
    if (c > 0) {
        for (int b = t; b < B_N; b += 256)
            if (zlab[b] == cz) { int p = atomicAdd(&s_n, 1); s_w[p] = final_idx[b]; }
    }
    __syncthreads();
    float inv = inv_u[cz];
    float zlr = 1.0f / (z_age[cz] + 1.0f);
    float fc = (float)c;
    float dv = (c > 0) ? fc : 1.0f;
    float f = zlr / dv;
    int n = s_n;
    const float* rowp = uw + (size_t)cz * Y_N;
    float* outp = outw + (size_t)cz * Y_N;
    for (int pass = 0; pass < 16; ++pass) {
        int e4 = pass * 256 + t;
        float4 u = *reinterpret_cast<const float4*>(rowp + e4 * 4);
        float4 un = make_float4(u.x*inv, u.y*inv, u.z*inv, u.w*inv);
        if (c > 0) {
            float4 s = make_float4(0.f, 0.f, 0.f, 0.f);
            for (int m = 0; m < n; ++m) {
                int d = s_w[m] - e4 * 4;
                if (d == 0) s.x += 1.f;
                else if (d == 1) s.y += 1.f;
                else if (d == 2) s.z += 1.f;
                else if (d == 3) s.w += 1.f;
            }
            un.x += f * (s.x - fc * un.x);
            un.y += f * (s.y - fc * un.y);
            un.z += f * (s.z - fc * un.z);
            un.w += f * (s.w - fc * un.w);
        }
        *reinterpret_cast<float4*>(outp + e4 * 4) = un;
    }
}

__global__ void thr_age_kernel(const int* __restrict__ cnt, const unsigned* __restrict__ segmin,
                               const float* __restrict__ y_age, const float* __restrict__ y_thr,
                               float* __restrict__ out_thr, float* __restrict__ out_age,
                               int* ctr) {
    int j = blockIdx.x * 256 + threadIdx.x;
    int c = cnt[j];
    float age = y_age[j];
    float thr = y_thr[j];
    float tn = thr;
    if (c > 0) {
        float lr = 1.0f / (age + 1.0f);
        float smin = dec_f(segmin[j]);
        float ycur = fminf(smin, 3.0f);
        if (ycur > 2.0f) ycur = 0.0f;
        tn = lr * ycur + (1.0f - lr) * thr;
    }
    out_thr[j] = tn;
    float an = age + (float)c;
    out_age[j] = an;
    unsigned long long m = __ballot(an >= 1.0f ? 1 : 0);
    if ((threadIdx.x & 63) == 0) atomicAdd(ctr + 1, (int)__popcll(m));
}

__global__ void zage_act_kernel(const int* __restrict__ zcnt, const float* __restrict__ z_age,
                                const int* __restrict__ ctr, float* __restrict__ out_zage,
                                float* __restrict__ out_act) {
    int i = blockIdx.x * 256 + threadIdx.x;
    if (i < Z_N) out_zage[i] = z_age[i] + (float)zcnt[i];
    if (i == 0) out_act[0] = (float)ctr[1];
}

extern "C" void kernel_launch(void* const* d_in, const int* in_sizes, int n_in,
                              void* d_out, int out_size, void* d_ws, size_t ws_size,
                              hipStream_t stream) {
    const float* x     = (const float*)d_in[0];
    const int*   z     = (const int*)d_in[1];
    const float* wxw   = (const float*)d_in[2];
    const float* wzw   = (const float*)d_in[3];
    const float* uw    = (const float*)d_in[4];
    const float* y_age = (const float*)d_in[5];
    const float* z_age = (const float*)d_in[6];
    const float* y_thr = (const float*)d_in[7];
    float* out = (float*)d_out;
    float* ws  = (float*)d_ws;

    float* inv_x  = ws + WS_INV_X;
    float* inv_wx = ws + WS_INV_WX;
    float* inv_wz = ws + WS_INV_WZ;
    float* inv_u  = ws + WS_INV_U;
    unsigned long long* pmax = (unsigned long long*)(ws + WS_PMAX);
    unsigned long long* pfb  = (unsigned long long*)(ws + WS_PFB);
    int* fidx = (int*)(ws + WS_FIDX);
    int* cnt  = (int*)(ws + WS_CNT);
    int* zcnt = (int*)(ws + WS_ZCNT);
    unsigned* segmin = (unsigned*)(ws + WS_SEGMIN);
    int* ctr = (int*)(ws + WS_CTR);

    init_kernel<<<64, 256, 0, stream>>>(pmax, pfb, cnt, segmin, zcnt, ctr);
    rownorm_kernel<<<B_N, 256, 0, stream>>>(x, X_N, inv_x);
    rownorm_kernel<<<Y_N, 256, 0, stream>>>(wxw, X_N, inv_wx);
    rownorm_kernel<<<Y_N, 256, 0, stream>>>(wzw, Z_N, inv_wz);
    rownorm_kernel<<<Z_N, 256, 0, stream>>>(uw, Y_N, inv_u);
    unact_kernel<<<Y_N / 256, 256, 0, stream>>>(y_age, ctr);
    gemm_argmax_kernel<<<dim3(Y_N / 128, B_N / 128), 256, 0, stream>>>(
        x, inv_x, wxw, inv_wx, wzw, inv_wz, z, y_age, pmax, pfb);
    finalize_kernel<<<B_N / 256, 256, 0, stream>>>(
        pmax, pfb, y_thr, y_age, z, ctr, fidx, cnt, segmin, zcnt, out + OFF_MAXRESP);
    wx_out_kernel<<<Y_N, 256, 0, stream>>>(wxw, inv_wx, x, inv_x, fidx, cnt, y_age, out + OFF_WX);
    wz_out_kernel<<<Y_N, 256, 0, stream>>>(wzw, inv_wz, z, fidx, cnt, y_age, out + OFF_WZ);
    u_out_kernel<<<Z_N, 256, 0, stream>>>(uw, inv_u, z, fidx, zcnt, z_age, out + OFF_U);
    thr_age_kernel<<<Y_N / 256, 256, 0, stream>>>(cnt, segmin, y_age, y_thr,
                                                  out + OFF_THR, out + OFF_AGE, ctr);
    zage_act_kernel<<<4, 256, 0, stream>>>(zcnt, z_age, ctr, out + OFF_ZAGE, out + OFF_ACT);
}